// Round 14
// baseline (113.407 us; speedup 1.0000x reference)
//
#include <hip/hip_runtime.h>
#include <hip/hip_fp16.h>
#include <math.h>
#include <stdint.h>

#define NBATCH 2
#define KBOX   512
#define NBOX   (NBATCH*KBOX)
#define CCH    256
#define NBIN   49                 // 7x7 bins
#define CPW    2                  // channels per wave
#define WAVES  4                  // waves per block
#define CHB    (CPW*WAVES)        // 8 channels per block
#define BPB    (CCH/CHB)          // 32 blocks per box
#define COUT   (CCH*NBIN)         // 12544 outputs per box
#define WCAP   1024               // floats per channel window; proven max 980 (+sentinel)
#define HDRN   32                 // ints per box header (8 scalars + 14 packed row words)
#define TAPN   (12*NBIN)          // 588 packed dwords per box (AoS: [bin][12])

typedef const uint32_t __attribute__((address_space(1)))* gas_u32p;
typedef uint32_t       __attribute__((address_space(3)))* las_u32p;

// ---- kernel 1: single-source FP; bitmap-rank row compaction; AoS tap layout ----
__global__ __launch_bounds__(64) void box_prep_kernel(
    const float* __restrict__ boxes, int* __restrict__ hdr, uint32_t* __restrict__ taps)
{
    const int m    = blockIdx.x;
    const int lane = threadIdx.x;

    __shared__ float    s_fy[14], s_fx[14];
    __shared__ int      s_slo[14], s_shi[14], s_xr[14];
    __shared__ int      s_vy[14], s_vx[14];
    __shared__ int      s_wsp4;
    __shared__ uint16_t s_roff[28];

    const float x1 = boxes[m*4+0];
    const float y1 = boxes[m*4+1];
    const float x2 = boxes[m*4+2];
    const float y2 = boxes[m*4+3];

    const float area = (x2 - x1) * (y2 - y1);
    const float size = sqrtf(area);
    float lvlf = floorf(4.0f + log2f(size / 224.0f + 1e-8f));
    lvlf = fminf(fmaxf(lvlf, 2.0f), 5.0f);
    const int lvl = (int)lvlf - 2;    // 0..3

    const int   H     = 256 >> lvl;
    const float scale = 0.25f / (float)(1 << lvl);
    const float Hf    = (float)H;

    const float bx1 = x1 * scale - 0.5f;
    const float by1 = y1 * scale - 0.5f;
    const float bin_w = (x2 * scale - 0.5f - bx1) / 7.0f;
    const float bin_h = (y2 * scale - 0.5f - by1) / 7.0f;

    if (lane == 0) {
        // ---- x pass: 14 samples, each floor computed exactly once ----
        int xls[14];
        #pragma unroll 1
        for (int i = 0; i < 14; ++i) {
            const float gx = ((float)i + 0.5f) * 0.5f;
            const float xx = bx1 + gx * bin_w;
            s_vx[i] = (xx >= -1.0f) && (xx <= Hf);
            const float xc = fmaxf(xx, 0.0f);
            const int xl = min((int)floorf(xc), H - 1);
            const int xh = min(xl + 1, H - 1);
            float fx = xc - (float)xl;
            if (xh == xl) fx = 0.0f;            // clamped pair: hi weight 0 (exact)
            s_fx[i] = fx;
            xls[i] = xl;
        }
        const int wx0a = xls[0] & ~3;                      // xls monotone -> min is xls[0]
        const int xh13 = min(xls[13] + 1, H - 1);          // max column touched
        const int wsp4 = ((xh13 - wx0a + 1 + 3) >> 2) << 2;
        s_wsp4 = wsp4;
        #pragma unroll 1
        for (int i = 0; i < 14; ++i) s_xr[i] = xls[i] - wx0a;

        // ---- y pass: floors once; 256-bit row bitmap ----
        unsigned long long bm[4] = {0ull, 0ull, 0ull, 0ull};
        int yls[14], yhs[14];
        #pragma unroll 1
        for (int j = 0; j < 14; ++j) {
            const float gy = ((float)j + 0.5f) * 0.5f;
            const float yy = by1 + gy * bin_h;
            s_vy[j] = (yy >= -1.0f) && (yy <= Hf);
            const float yc = fmaxf(yy, 0.0f);
            const int yl = min((int)floorf(yc), H - 1);
            const int yh = min(yl + 1, H - 1);
            s_fy[j] = yc - (float)yl;
            yls[j] = yl; yhs[j] = yh;
            bm[yl >> 6] |= 1ull << (yl & 63);
            bm[yh >> 6] |= 1ull << (yh & 63);
        }
        // rank = popcount below; list = set bits ascending (definitionally consistent)
        int cum[4];
        cum[0] = 0;
        cum[1] = cum[0] + (int)__popcll(bm[0]);
        cum[2] = cum[1] + (int)__popcll(bm[1]);
        cum[3] = cum[2] + (int)__popcll(bm[2]);
        const int nr = cum[3] + (int)__popcll(bm[3]);
        #pragma unroll 1
        for (int j = 0; j < 14; ++j) {
            const int yl = yls[j], yh = yhs[j];
            s_slo[j] = cum[yl >> 6] + (int)__popcll(bm[yl >> 6] & ((1ull << (yl & 63)) - 1ull));
            s_shi[j] = cum[yh >> 6] + (int)__popcll(bm[yh >> 6] & ((1ull << (yh & 63)) - 1ull));
        }
        int slot = 0;
        #pragma unroll 1
        for (int w = 0; w < 4; ++w) {
            unsigned long long t = bm[w];
            while (t) {
                const int b = __builtin_ctzll(t);
                t &= t - 1ull;
                s_roff[slot++] = (uint16_t)(((w << 6) + b) * H + wx0a);
            }
        }
        #pragma unroll 1
        for (int r = slot; r < 28; ++r) s_roff[r] = s_roff[slot - 1];

        // ---- header ----
        int* h = hdr + m * HDRN;
        const int qpr = wsp4 >> 2;
        const int nq  = nr * qpr;               // quads per channel window (<=245)
        h[0] = lvl;
        h[1] = H;
        h[2] = H * H;
        h[3] = qpr;
        h[4] = nq;
        h[5] = __float_as_int(1.0f / (float)qpr);
        h[6] = nq << 2;                         // sentinel float index
        h[7] = 0;
        uint32_t* hw = (uint32_t*)(h + 8);
        #pragma unroll 1
        for (int k = 0; k < 14; ++k)
            hw[k] = (uint32_t)s_roff[2*k] | ((uint32_t)s_roff[2*k+1] << 16);
    }
    __syncthreads();

    // ---- tap build: AoS layout [bin][12 dwords] -> 3 dwordx4 loads per lane ----
    if (lane < NBIN) {
        const int py = lane / 7;
        const int px = lane - py * 7;
        uint32_t* tp = taps + ((uint32_t)m * NBIN + lane) * 12u;
        const int wsp4 = s_wsp4;

        #pragma unroll
        for (int s = 0; s < 4; ++s) {
            const int j = 2*py + (s >> 1);
            const int i = 2*px + (s & 1);
            const float fy = s_fy[j];
            const float fx = s_fx[i];
            const float vm = (s_vy[j] && s_vx[i]) ? 0.25f : 0.0f;
            const float wyl = (1.0f - fy) * vm;
            const float wyh = fy * vm;

            const uint32_t olo = (uint32_t)(s_slo[j] * wsp4 + s_xr[i]);
            const uint32_t ohi = (uint32_t)(s_shi[j] * wsp4 + s_xr[i]);

            const __half2 wlo2 = __floats2half2_rn(wyl*(1.0f-fx), wyh*(1.0f-fx));
            const __half2 whi2 = __floats2half2_rn(wyl*fx,        wyh*fx);

            tp[s]     = olo | (ohi << 16);
            tp[4 + s] = *reinterpret_cast<const uint32_t*>(&wlo2);
            tp[8 + s] = *reinterpret_cast<const uint32_t*>(&whi2);
        }
    }
}

// -------- kernel 2: 2 channels per wave; converged staging; no inter-wave barrier --------
__global__ __launch_bounds__(256, 5) void roi_align_kernel(
    const float* __restrict__ f2, const float* __restrict__ f3,
    const float* __restrict__ f4, const float* __restrict__ f5,
    const int* __restrict__ hdr, const uint32_t* __restrict__ taps,
    float* __restrict__ out)
{
    const int bid  = blockIdx.x;
    const int m    = bid >> 5;        // consecutive blocks -> same box (BPB == 32)
    const int cg   = bid & 31;
    const int tid  = threadIdx.x;
    const int lane = tid & 63;
    const int wid  = tid >> 6;
    const int b    = m >> 9;          // batch (KBOX == 512)

    __shared__ float win[WAVES * CPW * WCAP];

    const int* h = hdr + m * HDRN;
    const int   lvl = h[0];
    const int   HH  = h[2];
    const int   qpr = h[3];
    const int   nq  = h[4];
    const float rq  = __int_as_float(h[5]);
    const int   nq4 = h[6];

    // packed row offsets: lane l holds word min(l,13); fan out via shfl
    const uint32_t roww = ((const uint32_t*)(h + 8))[min(lane, 13)];

    const float* fptr = (lvl == 0) ? f2 : (lvl == 1) ? f3 : (lvl == 2) ? f4 : f5;
    const int c0 = cg * CHB + wid * CPW;    // this wave's first channel
    const float* plane0 = fptr + ((size_t)(b * CCH + c0)) * HH;
    const float* plane1 = plane0 + HH;
    float* wb0 = win + (wid * CPW) * WCAP;  // wave-private LDS segments
    float* wb1 = wb0 + WCAP;

    // ---- stage 2 channels: one decode+shfl serves two 16B HBM->LDS loads ----
    // Converged loop: uniform trip count, shfl with ALL lanes active (r13 fix),
    // only the loads predicated.
    const int niter = (nq + 63) >> 6;
    for (int it = 0; it < niter; ++it) {
        const int iq  = (it << 6) + lane;
        const int iqc = min(iq, nq - 1);                   // clamp for address math
        const int slot = (int)(((float)iqc + 0.5f) * rq);  // iqc/qpr, exact (margin 0.5/qpr)
        const int cq   = iqc - slot * qpr;
        const uint32_t w2 = (uint32_t)__shfl((int)roww, slot >> 1, 64);
        const int roff = (((slot & 1) ? (int)(w2 >> 16) : (int)(w2 & 0xffffu))) + (cq << 2);
        if (iq < nq) {
            __builtin_amdgcn_global_load_lds(
                (gas_u32p)(const void*)(plane0 + roff),
                (las_u32p)(void*)(&wb0[it << 8]), 16, 0, 0);
            __builtin_amdgcn_global_load_lds(
                (gas_u32p)(const void*)(plane1 + roff),
                (las_u32p)(void*)(&wb1[it << 8]), 16, 0, 0);
        }
    }
    // sentinels: one-past-end slot a clamped x-hi pair read touches (weight 0)
    if (lane < CPW) win[(wid * CPW + lane) * WCAP + nq4] = 0.0f;

    // ---- taps: 3 coalesced dwordx4 loads per lane (AoS) ----
    const int l = (lane < NBIN) ? lane : NBIN - 1;
    const uint32_t* tp = taps + ((uint32_t)m * NBIN + l) * 12u;
    const uint4 tpo = *reinterpret_cast<const uint4*>(tp);
    const uint4 twl = *reinterpret_cast<const uint4*>(tp + 4);
    const uint4 twh = *reinterpret_cast<const uint4*>(tp + 8);

    // wave-local drain; fence the scheduler (rule #18)
    asm volatile("s_waitcnt vmcnt(0) lgkmcnt(0)" ::: "memory");
    __builtin_amdgcn_sched_barrier(0);

    // ---- compute: 2 channels x (16 LDS reads + 16 FMAs) + 2 stores ----
    const uint32_t pos[4] = {tpo.x, tpo.y, tpo.z, tpo.w};
    const uint32_t wls[4] = {twl.x, twl.y, twl.z, twl.w};
    const uint32_t whs[4] = {twh.x, twh.y, twh.z, twh.w};

    float acc0 = 0.0f, acc1 = 0.0f;
    #pragma unroll
    for (int s = 0; s < 4; ++s) {
        const int olo = (int)(pos[s] & 0xffffu);
        const int ohi = (int)(pos[s] >> 16);
        const float2 a  = __half22float2(*reinterpret_cast<const __half2*>(&wls[s]));
        const float2 bw = __half22float2(*reinterpret_cast<const __half2*>(&whs[s]));
        acc0 += a.x * wb0[olo] + bw.x * wb0[olo + 1];
        acc0 += a.y * wb0[ohi] + bw.y * wb0[ohi + 1];
        acc1 += a.x * wb1[olo] + bw.x * wb1[olo + 1];
        acc1 += a.y * wb1[ohi] + bw.y * wb1[ohi + 1];
    }

    if (lane < NBIN) {
        float* outp = out + (size_t)m * COUT + (size_t)c0 * NBIN + lane;
        __builtin_nontemporal_store(acc0, outp);
        __builtin_nontemporal_store(acc1, outp + NBIN);
    }
}

extern "C" void kernel_launch(void* const* d_in, const int* in_sizes, int n_in,
                              void* d_out, int out_size, void* d_ws, size_t ws_size,
                              hipStream_t stream) {
    const float* f2    = (const float*)d_in[0];
    const float* f3    = (const float*)d_in[1];
    const float* f4    = (const float*)d_in[2];
    const float* f5    = (const float*)d_in[3];
    const float* boxes = (const float*)d_in[4];
    float* outp = (float*)d_out;

    int*      hdr  = (int*)d_ws;                         // 1024*32*4 = 128 KB
    uint32_t* taps = (uint32_t*)d_ws + NBOX * HDRN;      // 1024*588*4 ≈ 2.4 MB

    box_prep_kernel<<<dim3(NBOX), dim3(64), 0, stream>>>(boxes, hdr, taps);
    roi_align_kernel<<<dim3(NBOX * BPB), dim3(256), 0, stream>>>(
        f2, f3, f4, f5, hdr, taps, outp);
}